// Round 1
// baseline (3077.923 us; speedup 1.0000x reference)
//
#include <hip/hip_runtime.h>
#include <cstddef>

#define NN 100000
#define NE 1600000

// ---------------------------------------------------------------------------
// conv1 edge pass: per edge e: msg = relu(x[src] + (ea[e] @ We1 + be1)) [128]
// scatter-add into aggr1[dst]. One wave per edge, 2 channels per lane.
// ---------------------------------------------------------------------------
__global__ __launch_bounds__(256) void conv1_edge(
    const float* __restrict__ x, const int* __restrict__ ei,
    const float* __restrict__ ea, const float* __restrict__ We,
    const float* __restrict__ be, float* __restrict__ aggr)
{
    __shared__ float2 sWe[16 * 64];   // [k][c/2], b64 reads conflict-free
    __shared__ float2 sbe[64];
    int t = threadIdx.x;
    const float2* W2 = (const float2*)We;
    for (int i = t; i < 1024; i += 256) sWe[i] = W2[i];
    if (t < 64) sbe[t] = ((const float2*)be)[t];
    __syncthreads();

    int lane = t & 63;
    int wid = (blockIdx.x << 2) + (t >> 6);
    int stride = gridDim.x << 2;
    for (int e = wid; e < NE; e += stride) {
        int src = __ldg(ei + e);
        int dst = __ldg(ei + NE + e);
        const float4* ap = (const float4*)(ea + (size_t)e * 16);
        float4 a0 = ap[0], a1 = ap[1], a2 = ap[2], a3 = ap[3];
        float av[16] = {a0.x,a0.y,a0.z,a0.w, a1.x,a1.y,a1.z,a1.w,
                        a2.x,a2.y,a2.z,a2.w, a3.x,a3.y,a3.z,a3.w};
        float2 acc = sbe[lane];
        #pragma unroll
        for (int k = 0; k < 16; k++) {
            float2 w = sWe[(k << 6) + lane];
            acc.x = fmaf(av[k], w.x, acc.x);
            acc.y = fmaf(av[k], w.y, acc.y);
        }
        float2 xv = *(const float2*)(x + (size_t)src * 128 + (lane << 1));
        float mx = fmaxf(xv.x + acc.x, 0.0f);
        float my = fmaxf(xv.y + acc.y, 0.0f);
        float* o = aggr + (size_t)dst * 128 + (lane << 1);
        unsafeAtomicAdd(o, mx);
        unsafeAtomicAdd(o + 1, my);
    }
}

// ---------------------------------------------------------------------------
// conv_mu + conv_logstd edge pass, fused (shared ea load + h[src] gather).
// Half-wave (32 lanes) per edge, 2 channels per lane, both trees.
// ---------------------------------------------------------------------------
__global__ __launch_bounds__(256) void conv23_edge(
    const float* __restrict__ h, const int* __restrict__ ei,
    const float* __restrict__ ea,
    const float* __restrict__ We2, const float* __restrict__ be2,
    const float* __restrict__ We3, const float* __restrict__ be3,
    float* __restrict__ aggr2, float* __restrict__ aggr3)
{
    __shared__ float2 sW2[16 * 32], sW3[16 * 32];
    __shared__ float2 sb2[32], sb3[32];
    int t = threadIdx.x;
    for (int i = t; i < 512; i += 256) {
        sW2[i] = ((const float2*)We2)[i];
        sW3[i] = ((const float2*)We3)[i];
    }
    if (t < 32) { sb2[t] = ((const float2*)be2)[t]; sb3[t] = ((const float2*)be3)[t]; }
    __syncthreads();

    int li = t & 31;
    int pid = (blockIdx.x << 3) + (t >> 5);   // 8 half-waves per block
    int stride = gridDim.x << 3;
    for (int e = pid; e < NE; e += stride) {
        int src = __ldg(ei + e);
        int dst = __ldg(ei + NE + e);
        const float4* ap = (const float4*)(ea + (size_t)e * 16);
        float4 a0 = ap[0], a1 = ap[1], a2 = ap[2], a3 = ap[3];
        float av[16] = {a0.x,a0.y,a0.z,a0.w, a1.x,a1.y,a1.z,a1.w,
                        a2.x,a2.y,a2.z,a2.w, a3.x,a3.y,a3.z,a3.w};
        float2 acc2 = sb2[li], acc3 = sb3[li];
        #pragma unroll
        for (int k = 0; k < 16; k++) {
            float2 w2 = sW2[(k << 5) + li];
            float2 w3 = sW3[(k << 5) + li];
            acc2.x = fmaf(av[k], w2.x, acc2.x);
            acc2.y = fmaf(av[k], w2.y, acc2.y);
            acc3.x = fmaf(av[k], w3.x, acc3.x);
            acc3.y = fmaf(av[k], w3.y, acc3.y);
        }
        float2 hv = *(const float2*)(h + (size_t)src * 64 + (li << 1));
        float m2x = fmaxf(hv.x + acc2.x, 0.0f);
        float m2y = fmaxf(hv.y + acc2.y, 0.0f);
        float m3x = fmaxf(hv.x + acc3.x, 0.0f);
        float m3y = fmaxf(hv.y + acc3.y, 0.0f);
        float* o2 = aggr2 + (size_t)dst * 64 + (li << 1);
        float* o3 = aggr3 + (size_t)dst * 64 + (li << 1);
        unsafeAtomicAdd(o2, m2x); unsafeAtomicAdd(o2 + 1, m2y);
        unsafeAtomicAdd(o3, m3x); unsafeAtomicAdd(o3 + 1, m3y);
    }
}

// ---------------------------------------------------------------------------
// Node MLP: out = epilogue( relu((xin+aggr) @ Wa + ba) @ Wb + bb )
// KIN -> 64 -> 64. 64 nodes per block, 256 threads, 4x4 register tiles.
// mode: 0 = none, 1 = relu, 2 = clip(-10, 10)
// ---------------------------------------------------------------------------
template <int KIN>
__global__ __launch_bounds__(256) void node_mlp(
    const float* __restrict__ xin, const float* __restrict__ aggr,
    const float* __restrict__ Wa, const float* __restrict__ ba,
    const float* __restrict__ Wb, const float* __restrict__ bb,
    float* __restrict__ out, int mode)
{
    constexpr int S0 = KIN + 4;       // padded input-tile stride (floats)
    constexpr int K4 = KIN / 4;
    __shared__ float sWa[KIN * 64];
    __shared__ float sWb[64 * 64];
    __shared__ float sh[64 * S0];     // input tile; reused (stride 68) for layer-1 out
    __shared__ float sba[64], sbb[64];
    int t = threadIdx.x;
    for (int i = t; i < KIN * 16; i += 256) ((float4*)sWa)[i] = ((const float4*)Wa)[i];
    for (int i = t; i < 1024; i += 256)     ((float4*)sWb)[i] = ((const float4*)Wb)[i];
    if (t < 64) { sba[t] = ba[t]; sbb[t] = bb[t]; }

    int nb = blockIdx.x << 6;
    for (int i = t; i < 64 * K4; i += 256) {
        int n = i / K4, k4 = i % K4;
        int node = nb + n;
        float4 v = make_float4(0.f, 0.f, 0.f, 0.f);
        if (node < NN) {
            float4 a = ((const float4*)(xin  + (size_t)node * KIN))[k4];
            float4 b = ((const float4*)(aggr + (size_t)node * KIN))[k4];
            v = make_float4(a.x + b.x, a.y + b.y, a.z + b.z, a.w + b.w);
        }
        *(float4*)&sh[n * S0 + (k4 << 2)] = v;
    }
    __syncthreads();

    int tx = t & 15, ty = t >> 4;
    int c0 = tx << 2, n0 = ty << 2;

    // ---- layer 1: [64 x KIN] @ [KIN x 64] ----
    float4 b1 = *(const float4*)&sba[c0];
    float acc[4][4];
    #pragma unroll
    for (int i = 0; i < 4; i++) { acc[i][0] = b1.x; acc[i][1] = b1.y; acc[i][2] = b1.z; acc[i][3] = b1.w; }
    for (int k4 = 0; k4 < K4; k4++) {
        int k = k4 << 2;
        float4 w0 = *(const float4*)&sWa[((k + 0) << 6) + c0];
        float4 w1 = *(const float4*)&sWa[((k + 1) << 6) + c0];
        float4 w2 = *(const float4*)&sWa[((k + 2) << 6) + c0];
        float4 w3 = *(const float4*)&sWa[((k + 3) << 6) + c0];
        #pragma unroll
        for (int i = 0; i < 4; i++) {
            float4 hv = *(const float4*)&sh[(n0 + i) * S0 + k];
            acc[i][0] = fmaf(hv.x, w0.x, acc[i][0]); acc[i][1] = fmaf(hv.x, w0.y, acc[i][1]);
            acc[i][2] = fmaf(hv.x, w0.z, acc[i][2]); acc[i][3] = fmaf(hv.x, w0.w, acc[i][3]);
            acc[i][0] = fmaf(hv.y, w1.x, acc[i][0]); acc[i][1] = fmaf(hv.y, w1.y, acc[i][1]);
            acc[i][2] = fmaf(hv.y, w1.z, acc[i][2]); acc[i][3] = fmaf(hv.y, w1.w, acc[i][3]);
            acc[i][0] = fmaf(hv.z, w2.x, acc[i][0]); acc[i][1] = fmaf(hv.z, w2.y, acc[i][1]);
            acc[i][2] = fmaf(hv.z, w2.z, acc[i][2]); acc[i][3] = fmaf(hv.z, w2.w, acc[i][3]);
            acc[i][0] = fmaf(hv.w, w3.x, acc[i][0]); acc[i][1] = fmaf(hv.w, w3.y, acc[i][1]);
            acc[i][2] = fmaf(hv.w, w3.z, acc[i][2]); acc[i][3] = fmaf(hv.w, w3.w, acc[i][3]);
        }
    }
    __syncthreads();   // all reads of input tile done
    #pragma unroll
    for (int i = 0; i < 4; i++) {
        float4 v = make_float4(fmaxf(acc[i][0], 0.f), fmaxf(acc[i][1], 0.f),
                               fmaxf(acc[i][2], 0.f), fmaxf(acc[i][3], 0.f));
        *(float4*)&sh[(n0 + i) * 68 + c0] = v;   // layer-1 out, stride 68
    }
    __syncthreads();

    // ---- layer 2: [64 x 64] @ [64 x 64] ----
    float4 b2 = *(const float4*)&sbb[c0];
    float acc2[4][4];
    #pragma unroll
    for (int i = 0; i < 4; i++) { acc2[i][0] = b2.x; acc2[i][1] = b2.y; acc2[i][2] = b2.z; acc2[i][3] = b2.w; }
    for (int k4 = 0; k4 < 16; k4++) {
        int k = k4 << 2;
        float4 w0 = *(const float4*)&sWb[((k + 0) << 6) + c0];
        float4 w1 = *(const float4*)&sWb[((k + 1) << 6) + c0];
        float4 w2 = *(const float4*)&sWb[((k + 2) << 6) + c0];
        float4 w3 = *(const float4*)&sWb[((k + 3) << 6) + c0];
        #pragma unroll
        for (int i = 0; i < 4; i++) {
            float4 hv = *(const float4*)&sh[(n0 + i) * 68 + k];
            acc2[i][0] = fmaf(hv.x, w0.x, acc2[i][0]); acc2[i][1] = fmaf(hv.x, w0.y, acc2[i][1]);
            acc2[i][2] = fmaf(hv.x, w0.z, acc2[i][2]); acc2[i][3] = fmaf(hv.x, w0.w, acc2[i][3]);
            acc2[i][0] = fmaf(hv.y, w1.x, acc2[i][0]); acc2[i][1] = fmaf(hv.y, w1.y, acc2[i][1]);
            acc2[i][2] = fmaf(hv.y, w1.z, acc2[i][2]); acc2[i][3] = fmaf(hv.y, w1.w, acc2[i][3]);
            acc2[i][0] = fmaf(hv.z, w2.x, acc2[i][0]); acc2[i][1] = fmaf(hv.z, w2.y, acc2[i][1]);
            acc2[i][2] = fmaf(hv.z, w2.z, acc2[i][2]); acc2[i][3] = fmaf(hv.z, w2.w, acc2[i][3]);
            acc2[i][0] = fmaf(hv.w, w3.x, acc2[i][0]); acc2[i][1] = fmaf(hv.w, w3.y, acc2[i][1]);
            acc2[i][2] = fmaf(hv.w, w3.z, acc2[i][2]); acc2[i][3] = fmaf(hv.w, w3.w, acc2[i][3]);
        }
    }

    #pragma unroll
    for (int i = 0; i < 4; i++) {
        int node = nb + n0 + i;
        if (node >= NN) continue;
        float4 v = make_float4(acc2[i][0], acc2[i][1], acc2[i][2], acc2[i][3]);
        if (mode == 1) {
            v = make_float4(fmaxf(v.x, 0.f), fmaxf(v.y, 0.f), fmaxf(v.z, 0.f), fmaxf(v.w, 0.f));
        } else if (mode == 2) {
            v = make_float4(fminf(fmaxf(v.x, -10.f), 10.f), fminf(fmaxf(v.y, -10.f), 10.f),
                            fminf(fmaxf(v.z, -10.f), 10.f), fminf(fmaxf(v.w, -10.f), 10.f));
        }
        *(float4*)(out + (size_t)node * 64 + c0) = v;
    }
}

extern "C" void kernel_launch(void* const* d_in, const int* in_sizes, int n_in,
                              void* d_out, int out_size, void* d_ws, size_t ws_size,
                              hipStream_t stream)
{
    const float* x   = (const float*)d_in[0];
    const int*   ei  = (const int*)  d_in[1];
    const float* ea  = (const float*)d_in[2];
    const float* We1 = (const float*)d_in[3];
    const float* be1 = (const float*)d_in[4];
    const float* W1a = (const float*)d_in[5];
    const float* b1a = (const float*)d_in[6];
    const float* W1b = (const float*)d_in[7];
    const float* b1b = (const float*)d_in[8];
    const float* We2 = (const float*)d_in[9];
    const float* be2 = (const float*)d_in[10];
    const float* W2a = (const float*)d_in[11];
    const float* b2a = (const float*)d_in[12];
    const float* W2b = (const float*)d_in[13];
    const float* b2b = (const float*)d_in[14];
    const float* We3 = (const float*)d_in[15];
    const float* be3 = (const float*)d_in[16];
    const float* W3a = (const float*)d_in[17];
    const float* b3a = (const float*)d_in[18];
    const float* W3b = (const float*)d_in[19];
    const float* b3b = (const float*)d_in[20];

    float* out = (float*)d_out;
    float* ws = (float*)d_ws;
    float* aggr1 = ws;                 // 100000*128 = 12.8M floats
    float* h     = ws + 12800000;      // 100000*64  =  6.4M floats
    float* aggr2 = ws + 19200000;      //  6.4M floats
    float* aggr3 = ws + 25600000;      //  6.4M floats  (total 128 MB)

    hipMemsetAsync(aggr1, 0, 12800000ull * sizeof(float), stream);
    hipMemsetAsync(aggr2, 0, 12800000ull * sizeof(float), stream);  // aggr2 + aggr3 contiguous

    conv1_edge<<<4096, 256, 0, stream>>>(x, ei, ea, We1, be1, aggr1);
    node_mlp<128><<<(NN + 63) / 64, 256, 0, stream>>>(x, aggr1, W1a, b1a, W1b, b1b, h, 1);
    conv23_edge<<<4096, 256, 0, stream>>>(h, ei, ea, We2, be2, We3, be3, aggr2, aggr3);
    node_mlp<64><<<(NN + 63) / 64, 256, 0, stream>>>(h, aggr2, W2a, b2a, W2b, b2b, out, 0);
    node_mlp<64><<<(NN + 63) / 64, 256, 0, stream>>>(h, aggr3, W3a, b3a, W3b, b3b, out + (size_t)NN * 64, 2);
}

// Round 2
// 1534.977 us; speedup vs baseline: 2.0052x; 2.0052x over previous
//
#include <hip/hip_runtime.h>
#include <cstddef>

#define NN 100000
#define NE 1600000

// ===========================================================================
// CSR build: histogram(dst) -> exclusive scan -> scatter edge ids (perm)
// ===========================================================================
__global__ __launch_bounds__(256) void hist_dst(const int* __restrict__ ei,
                                                int* __restrict__ deg)
{
    int i = blockIdx.x * 256 + threadIdx.x;
    int stride = gridDim.x * 256;
    for (int e = i; e < NE; e += stride)
        atomicAdd(&deg[ei[NE + e]], 1);
}

// Single-block exclusive scan over NN degrees. Writes off[0..NN] and
// rewrites deg[i] = off[i] (deg then serves as the scatter cursor).
__global__ __launch_bounds__(1024) void scan_deg(int* __restrict__ deg,
                                                 int* __restrict__ off)
{
    __shared__ int s[1024];
    __shared__ int carry_s;
    int t = threadIdx.x;
    if (t == 0) carry_s = 0;
    __syncthreads();
    for (int base = 0; base < NN; base += 1024) {
        int i = base + t;
        int v = (i < NN) ? deg[i] : 0;
        s[t] = v;
        __syncthreads();
        #pragma unroll
        for (int o = 1; o < 1024; o <<= 1) {
            int u = (t >= o) ? s[t - o] : 0;
            __syncthreads();
            s[t] += u;
            __syncthreads();
        }
        int incl = s[t];
        int excl = incl - v;
        int carry = carry_s;
        if (i < NN) { off[i] = carry + excl; deg[i] = carry + excl; }
        __syncthreads();
        if (t == 1023) carry_s = carry + incl;   // incl at t=1023 == chunk total
        __syncthreads();
    }
    if (t == 0) off[NN] = carry_s;
}

__global__ __launch_bounds__(256) void scatter_perm(const int* __restrict__ ei,
                                                    int* __restrict__ cur,
                                                    int* __restrict__ perm)
{
    int i = blockIdx.x * 256 + threadIdx.x;
    int stride = gridDim.x * 256;
    for (int e = i; e < NE; e += stride) {
        int d = ei[NE + e];
        int pos = atomicAdd(&cur[d], 1);
        perm[pos] = e;
    }
}

// ===========================================================================
// conv1 gather: one wave per node, 2 channels/lane (128 ch).
// aggr1[n] = sum_{e: dst=n} relu(x[src_e] + ea[e] @ We1 + be1)
// ===========================================================================
__global__ __launch_bounds__(256) void conv1_gather(
    const float* __restrict__ x, const int* __restrict__ ei,
    const float* __restrict__ ea, const float* __restrict__ We,
    const float* __restrict__ be, const int* __restrict__ off,
    const int* __restrict__ perm, float* __restrict__ aggr)
{
    __shared__ float2 sWe[16 * 64];
    __shared__ float2 sbe[64];
    int t = threadIdx.x;
    const float2* W2 = (const float2*)We;
    for (int i = t; i < 1024; i += 256) sWe[i] = W2[i];
    if (t < 64) sbe[t] = ((const float2*)be)[t];
    __syncthreads();

    int lane = t & 63;
    int n = blockIdx.x * 4 + (t >> 6);
    if (n >= NN) return;
    int j0 = off[n], j1 = off[n + 1];
    float2 bias = sbe[lane];
    float2 acc = make_float2(0.f, 0.f);
    for (int j = j0; j < j1; j++) {
        int e = perm[j];
        int src = ei[e];
        const float4* ap = (const float4*)(ea + (size_t)e * 16);
        float4 a0 = ap[0], a1 = ap[1], a2 = ap[2], a3 = ap[3];
        float av[16] = {a0.x,a0.y,a0.z,a0.w, a1.x,a1.y,a1.z,a1.w,
                        a2.x,a2.y,a2.z,a2.w, a3.x,a3.y,a3.z,a3.w};
        float2 m = bias;
        #pragma unroll
        for (int k = 0; k < 16; k++) {
            float2 w = sWe[(k << 6) + lane];
            m.x = fmaf(av[k], w.x, m.x);
            m.y = fmaf(av[k], w.y, m.y);
        }
        float2 xv = *(const float2*)(x + (size_t)src * 128 + (lane << 1));
        acc.x += fmaxf(xv.x + m.x, 0.0f);
        acc.y += fmaxf(xv.y + m.y, 0.0f);
    }
    *(float2*)(aggr + (size_t)n * 128 + (lane << 1)) = acc;
}

// ===========================================================================
// conv_mu + conv_logstd gather, fused: half-wave per node, 2 ch/lane, 2 trees.
// ===========================================================================
__global__ __launch_bounds__(256) void conv23_gather(
    const float* __restrict__ h, const int* __restrict__ ei,
    const float* __restrict__ ea,
    const float* __restrict__ We2, const float* __restrict__ be2,
    const float* __restrict__ We3, const float* __restrict__ be3,
    const int* __restrict__ off, const int* __restrict__ perm,
    float* __restrict__ aggr2, float* __restrict__ aggr3)
{
    __shared__ float2 sW2[16 * 32], sW3[16 * 32];
    __shared__ float2 sb2[32], sb3[32];
    int t = threadIdx.x;
    for (int i = t; i < 512; i += 256) {
        sW2[i] = ((const float2*)We2)[i];
        sW3[i] = ((const float2*)We3)[i];
    }
    if (t < 32) { sb2[t] = ((const float2*)be2)[t]; sb3[t] = ((const float2*)be3)[t]; }
    __syncthreads();

    int li = t & 31;
    int n = blockIdx.x * 8 + (t >> 5);
    if (n >= NN) return;
    int j0 = off[n], j1 = off[n + 1];
    float2 bias2 = sb2[li], bias3 = sb3[li];
    float2 acc2 = make_float2(0.f, 0.f), acc3 = make_float2(0.f, 0.f);
    for (int j = j0; j < j1; j++) {
        int e = perm[j];
        int src = ei[e];
        const float4* ap = (const float4*)(ea + (size_t)e * 16);
        float4 a0 = ap[0], a1 = ap[1], a2 = ap[2], a3 = ap[3];
        float av[16] = {a0.x,a0.y,a0.z,a0.w, a1.x,a1.y,a1.z,a1.w,
                        a2.x,a2.y,a2.z,a2.w, a3.x,a3.y,a3.z,a3.w};
        float2 m2 = bias2, m3 = bias3;
        #pragma unroll
        for (int k = 0; k < 16; k++) {
            float2 w2 = sW2[(k << 5) + li];
            float2 w3 = sW3[(k << 5) + li];
            m2.x = fmaf(av[k], w2.x, m2.x);
            m2.y = fmaf(av[k], w2.y, m2.y);
            m3.x = fmaf(av[k], w3.x, m3.x);
            m3.y = fmaf(av[k], w3.y, m3.y);
        }
        float2 hv = *(const float2*)(h + (size_t)src * 64 + (li << 1));
        acc2.x += fmaxf(hv.x + m2.x, 0.0f);
        acc2.y += fmaxf(hv.y + m2.y, 0.0f);
        acc3.x += fmaxf(hv.x + m3.x, 0.0f);
        acc3.y += fmaxf(hv.y + m3.y, 0.0f);
    }
    *(float2*)(aggr2 + (size_t)n * 64 + (li << 1)) = acc2;
    *(float2*)(aggr3 + (size_t)n * 64 + (li << 1)) = acc3;
}

// ===========================================================================
// Node MLP: out = epilogue( relu((xin+aggr) @ Wa + ba) @ Wb + bb )
// KIN -> 64 -> 64. 64 nodes per block, 256 threads, 4x4 register tiles.
// mode: 0 = none, 1 = relu, 2 = clip(-10, 10)
// ===========================================================================
template <int KIN>
__global__ __launch_bounds__(256) void node_mlp(
    const float* __restrict__ xin, const float* __restrict__ aggr,
    const float* __restrict__ Wa, const float* __restrict__ ba,
    const float* __restrict__ Wb, const float* __restrict__ bb,
    float* __restrict__ out, int mode)
{
    constexpr int S0 = KIN + 4;
    constexpr int K4 = KIN / 4;
    __shared__ float sWa[KIN * 64];
    __shared__ float sWb[64 * 64];
    __shared__ float sh[64 * S0];
    __shared__ float sba[64], sbb[64];
    int t = threadIdx.x;
    for (int i = t; i < KIN * 16; i += 256) ((float4*)sWa)[i] = ((const float4*)Wa)[i];
    for (int i = t; i < 1024; i += 256)     ((float4*)sWb)[i] = ((const float4*)Wb)[i];
    if (t < 64) { sba[t] = ba[t]; sbb[t] = bb[t]; }

    int nb = blockIdx.x << 6;
    for (int i = t; i < 64 * K4; i += 256) {
        int n = i / K4, k4 = i % K4;
        int node = nb + n;
        float4 v = make_float4(0.f, 0.f, 0.f, 0.f);
        if (node < NN) {
            float4 a = ((const float4*)(xin  + (size_t)node * KIN))[k4];
            float4 b = ((const float4*)(aggr + (size_t)node * KIN))[k4];
            v = make_float4(a.x + b.x, a.y + b.y, a.z + b.z, a.w + b.w);
        }
        *(float4*)&sh[n * S0 + (k4 << 2)] = v;
    }
    __syncthreads();

    int tx = t & 15, ty = t >> 4;
    int c0 = tx << 2, n0 = ty << 2;

    float4 b1 = *(const float4*)&sba[c0];
    float acc[4][4];
    #pragma unroll
    for (int i = 0; i < 4; i++) { acc[i][0] = b1.x; acc[i][1] = b1.y; acc[i][2] = b1.z; acc[i][3] = b1.w; }
    for (int k4 = 0; k4 < K4; k4++) {
        int k = k4 << 2;
        float4 w0 = *(const float4*)&sWa[((k + 0) << 6) + c0];
        float4 w1 = *(const float4*)&sWa[((k + 1) << 6) + c0];
        float4 w2 = *(const float4*)&sWa[((k + 2) << 6) + c0];
        float4 w3 = *(const float4*)&sWa[((k + 3) << 6) + c0];
        #pragma unroll
        for (int i = 0; i < 4; i++) {
            float4 hv = *(const float4*)&sh[(n0 + i) * S0 + k];
            acc[i][0] = fmaf(hv.x, w0.x, acc[i][0]); acc[i][1] = fmaf(hv.x, w0.y, acc[i][1]);
            acc[i][2] = fmaf(hv.x, w0.z, acc[i][2]); acc[i][3] = fmaf(hv.x, w0.w, acc[i][3]);
            acc[i][0] = fmaf(hv.y, w1.x, acc[i][0]); acc[i][1] = fmaf(hv.y, w1.y, acc[i][1]);
            acc[i][2] = fmaf(hv.y, w1.z, acc[i][2]); acc[i][3] = fmaf(hv.y, w1.w, acc[i][3]);
            acc[i][0] = fmaf(hv.z, w2.x, acc[i][0]); acc[i][1] = fmaf(hv.z, w2.y, acc[i][1]);
            acc[i][2] = fmaf(hv.z, w2.z, acc[i][2]); acc[i][3] = fmaf(hv.z, w2.w, acc[i][3]);
            acc[i][0] = fmaf(hv.w, w3.x, acc[i][0]); acc[i][1] = fmaf(hv.w, w3.y, acc[i][1]);
            acc[i][2] = fmaf(hv.w, w3.z, acc[i][2]); acc[i][3] = fmaf(hv.w, w3.w, acc[i][3]);
        }
    }
    __syncthreads();
    #pragma unroll
    for (int i = 0; i < 4; i++) {
        float4 v = make_float4(fmaxf(acc[i][0], 0.f), fmaxf(acc[i][1], 0.f),
                               fmaxf(acc[i][2], 0.f), fmaxf(acc[i][3], 0.f));
        *(float4*)&sh[(n0 + i) * 68 + c0] = v;
    }
    __syncthreads();

    float4 b2 = *(const float4*)&sbb[c0];
    float acc2[4][4];
    #pragma unroll
    for (int i = 0; i < 4; i++) { acc2[i][0] = b2.x; acc2[i][1] = b2.y; acc2[i][2] = b2.z; acc2[i][3] = b2.w; }
    for (int k4 = 0; k4 < 16; k4++) {
        int k = k4 << 2;
        float4 w0 = *(const float4*)&sWb[((k + 0) << 6) + c0];
        float4 w1 = *(const float4*)&sWb[((k + 1) << 6) + c0];
        float4 w2 = *(const float4*)&sWb[((k + 2) << 6) + c0];
        float4 w3 = *(const float4*)&sWb[((k + 3) << 6) + c0];
        #pragma unroll
        for (int i = 0; i < 4; i++) {
            float4 hv = *(const float4*)&sh[(n0 + i) * 68 + k];
            acc2[i][0] = fmaf(hv.x, w0.x, acc2[i][0]); acc2[i][1] = fmaf(hv.x, w0.y, acc2[i][1]);
            acc2[i][2] = fmaf(hv.x, w0.z, acc2[i][2]); acc2[i][3] = fmaf(hv.x, w0.w, acc2[i][3]);
            acc2[i][0] = fmaf(hv.y, w1.x, acc2[i][0]); acc2[i][1] = fmaf(hv.y, w1.y, acc2[i][1]);
            acc2[i][2] = fmaf(hv.y, w1.z, acc2[i][2]); acc2[i][3] = fmaf(hv.y, w1.w, acc2[i][3]);
            acc2[i][0] = fmaf(hv.z, w2.x, acc2[i][0]); acc2[i][1] = fmaf(hv.z, w2.y, acc2[i][1]);
            acc2[i][2] = fmaf(hv.z, w2.z, acc2[i][2]); acc2[i][3] = fmaf(hv.z, w2.w, acc2[i][3]);
            acc2[i][0] = fmaf(hv.w, w3.x, acc2[i][0]); acc2[i][1] = fmaf(hv.w, w3.y, acc2[i][1]);
            acc2[i][2] = fmaf(hv.w, w3.z, acc2[i][2]); acc2[i][3] = fmaf(hv.w, w3.w, acc2[i][3]);
        }
    }

    #pragma unroll
    for (int i = 0; i < 4; i++) {
        int node = nb + n0 + i;
        if (node >= NN) continue;
        float4 v = make_float4(acc2[i][0], acc2[i][1], acc2[i][2], acc2[i][3]);
        if (mode == 1) {
            v = make_float4(fmaxf(v.x, 0.f), fmaxf(v.y, 0.f), fmaxf(v.z, 0.f), fmaxf(v.w, 0.f));
        } else if (mode == 2) {
            v = make_float4(fminf(fmaxf(v.x, -10.f), 10.f), fminf(fmaxf(v.y, -10.f), 10.f),
                            fminf(fmaxf(v.z, -10.f), 10.f), fminf(fmaxf(v.w, -10.f), 10.f));
        }
        *(float4*)(out + (size_t)node * 64 + c0) = v;
    }
}

extern "C" void kernel_launch(void* const* d_in, const int* in_sizes, int n_in,
                              void* d_out, int out_size, void* d_ws, size_t ws_size,
                              hipStream_t stream)
{
    const float* x   = (const float*)d_in[0];
    const int*   ei  = (const int*)  d_in[1];
    const float* ea  = (const float*)d_in[2];
    const float* We1 = (const float*)d_in[3];
    const float* be1 = (const float*)d_in[4];
    const float* W1a = (const float*)d_in[5];
    const float* b1a = (const float*)d_in[6];
    const float* W1b = (const float*)d_in[7];
    const float* b1b = (const float*)d_in[8];
    const float* We2 = (const float*)d_in[9];
    const float* be2 = (const float*)d_in[10];
    const float* W2a = (const float*)d_in[11];
    const float* b2a = (const float*)d_in[12];
    const float* W2b = (const float*)d_in[13];
    const float* b2b = (const float*)d_in[14];
    const float* We3 = (const float*)d_in[15];
    const float* be3 = (const float*)d_in[16];
    const float* W3a = (const float*)d_in[17];
    const float* b3a = (const float*)d_in[18];
    const float* W3b = (const float*)d_in[19];
    const float* b3b = (const float*)d_in[20];

    float* out = (float*)d_out;
    float* ws = (float*)d_ws;
    // float scratch: aggr1 [12.8M] (later aliased by aggr2/aggr3), h [6.4M]
    float* aggr1 = ws;
    float* h     = ws + 12800000;
    float* aggr2 = ws;              // aliases aggr1 (dead after node_mlp<128>)
    float* aggr3 = ws + 6400000;
    // int scratch after 19.2M floats: off [NN+1], cur [NN], perm [NE]
    int* ibase = (int*)(ws + 19200000);
    int* off  = ibase;
    int* cur  = ibase + (NN + 1);
    int* perm = ibase + (2 * NN + 2);

    // ---- CSR build (shared by conv1 and conv23) ----
    hipMemsetAsync(cur, 0, (size_t)NN * sizeof(int), stream);
    hist_dst<<<2048, 256, 0, stream>>>(ei, cur);
    scan_deg<<<1, 1024, 0, stream>>>(cur, off);   // cur becomes scatter cursor
    scatter_perm<<<2048, 256, 0, stream>>>(ei, cur, perm);

    // ---- layer 1 ----
    conv1_gather<<<(NN + 3) / 4, 256, 0, stream>>>(x, ei, ea, We1, be1, off, perm, aggr1);
    node_mlp<128><<<(NN + 63) / 64, 256, 0, stream>>>(x, aggr1, W1a, b1a, W1b, b1b, h, 1);

    // ---- layers 2+3 (fused edge pass) ----
    conv23_gather<<<(NN + 7) / 8, 256, 0, stream>>>(h, ei, ea, We2, be2, We3, be3,
                                                    off, perm, aggr2, aggr3);
    node_mlp<64><<<(NN + 63) / 64, 256, 0, stream>>>(h, aggr2, W2a, b2a, W2b, b2b, out, 0);
    node_mlp<64><<<(NN + 63) / 64, 256, 0, stream>>>(h, aggr3, W3a, b3a, W3b, b3b,
                                                     out + (size_t)NN * 64, 2);
}

// Round 4
// 1361.030 us; speedup vs baseline: 2.2615x; 1.1278x over previous
//
#include <hip/hip_runtime.h>
#include <cstddef>

#define NN 100000
#define NE 1600000

// ===========================================================================
// CSR build: histogram(dst) -> exclusive scan -> scatter {e, src} records
// ===========================================================================
__global__ __launch_bounds__(256) void hist_dst(const int* __restrict__ ei,
                                                int* __restrict__ deg)
{
    int i = blockIdx.x * 256 + threadIdx.x;
    int stride = gridDim.x * 256;
    for (int e = i; e < NE; e += stride)
        atomicAdd(&deg[ei[NE + e]], 1);
}

// Single-block exclusive scan over NN degrees. Writes off[0..NN] and
// rewrites deg[i] = off[i] (deg then serves as the scatter cursor).
__global__ __launch_bounds__(1024) void scan_deg(int* __restrict__ deg,
                                                 int* __restrict__ off)
{
    __shared__ int s[1024];
    __shared__ int carry_s;
    int t = threadIdx.x;
    if (t == 0) carry_s = 0;
    __syncthreads();
    for (int base = 0; base < NN; base += 1024) {
        int i = base + t;
        int v = (i < NN) ? deg[i] : 0;
        s[t] = v;
        __syncthreads();
        #pragma unroll
        for (int o = 1; o < 1024; o <<= 1) {
            int u = (t >= o) ? s[t - o] : 0;
            __syncthreads();
            s[t] += u;
            __syncthreads();
        }
        int incl = s[t];
        int excl = incl - v;
        int carry = carry_s;
        if (i < NN) { off[i] = carry + excl; deg[i] = carry + excl; }
        __syncthreads();
        if (t == 1023) carry_s = carry + incl;
        __syncthreads();
    }
    if (t == 0) off[NN] = carry_s;
}

__global__ __launch_bounds__(256) void scatter_perm(const int* __restrict__ ei,
                                                    int* __restrict__ cur,
                                                    int2* __restrict__ perm2)
{
    int i = blockIdx.x * 256 + threadIdx.x;
    int stride = gridDim.x * 256;
    for (int e = i; e < NE; e += stride) {
        int s = ei[e];
        int d = ei[NE + e];
        int pos = atomicAdd(&cur[d], 1);
        perm2[pos] = make_int2(e, s);
    }
}

// ===========================================================================
// conv1 gather: one FULL wave per node (node is wave-uniform =>
// readfirstlane is legal). 2 channels/lane (128 ch), 2-deep pipeline.
// aggr1[n] = sum_{e: dst=n} relu(x[src_e] + ea[e] @ We1 + be1)
// ===========================================================================
__global__ __launch_bounds__(256) void conv1_gather(
    const float* __restrict__ x, const float* __restrict__ ea,
    const float* __restrict__ We, const float* __restrict__ be,
    const int* __restrict__ off, const int2* __restrict__ perm2,
    float* __restrict__ aggr)
{
    __shared__ float2 sWe[16 * 64];
    __shared__ float2 sbe[64];
    int t = threadIdx.x;
    const float2* W2 = (const float2*)We;
    for (int i = t; i < 1024; i += 256) sWe[i] = W2[i];
    if (t < 64) sbe[t] = ((const float2*)be)[t];
    __syncthreads();

    int lane = t & 63;
    int n = blockIdx.x * 4 + (t >> 6);
    if (n >= NN) return;
    int j0 = off[n], j1 = off[n + 1];
    float2 bias = sbe[lane];
    float2 acc = make_float2(0.f, 0.f);

    int2 es1 = make_int2(0, 0);
    float4 c0, c1, c2, c3; float2 cx;
    c0 = c1 = c2 = c3 = make_float4(0.f, 0.f, 0.f, 0.f);
    cx = make_float2(0.f, 0.f);
    if (j0 < j1) {
        int2 es0 = perm2[j0];
        int e = __builtin_amdgcn_readfirstlane(es0.x);
        int s = __builtin_amdgcn_readfirstlane(es0.y);
        const float4* ap = (const float4*)(ea + (size_t)e * 16);
        c0 = ap[0]; c1 = ap[1]; c2 = ap[2]; c3 = ap[3];
        cx = *(const float2*)(x + (size_t)s * 128 + (lane << 1));
        if (j0 + 1 < j1) es1 = perm2[j0 + 1];
    }
    for (int j = j0; j < j1; j++) {
        // ---- prefetch edge j+1 data, edge j+2 record ----
        float4 p0, p1, p2, p3; float2 px; int2 es2 = es1;
        p0 = c0; p1 = c1; p2 = c2; p3 = c3; px = cx;
        if (j + 1 < j1) {
            int e = __builtin_amdgcn_readfirstlane(es1.x);
            int s = __builtin_amdgcn_readfirstlane(es1.y);
            const float4* ap = (const float4*)(ea + (size_t)e * 16);
            p0 = ap[0]; p1 = ap[1]; p2 = ap[2]; p3 = ap[3];
            px = *(const float2*)(x + (size_t)s * 128 + (lane << 1));
            if (j + 2 < j1) es2 = perm2[j + 2];
        }
        // ---- compute edge j ----
        float av[16] = {c0.x,c0.y,c0.z,c0.w, c1.x,c1.y,c1.z,c1.w,
                        c2.x,c2.y,c2.z,c2.w, c3.x,c3.y,c3.z,c3.w};
        float2 m = bias;
        #pragma unroll
        for (int k = 0; k < 16; k++) {
            float2 w = sWe[(k << 6) + lane];
            m.x = fmaf(av[k], w.x, m.x);
            m.y = fmaf(av[k], w.y, m.y);
        }
        acc.x += fmaxf(cx.x + m.x, 0.0f);
        acc.y += fmaxf(cx.y + m.y, 0.0f);
        // ---- rotate ----
        c0 = p0; c1 = p1; c2 = p2; c3 = p3; cx = px;
        es1 = es2;
    }
    *(float2*)(aggr + (size_t)n * 128 + (lane << 1)) = acc;
}

// ===========================================================================
// conv_mu + conv_logstd gather, fused: one FULL wave per node (wave-uniform
// node => readfirstlane legal). Trees split across the wave: lanes 0-31 = mu
// (W2), lanes 32-63 = logstd (W3), 2 channels/lane. 2-deep pipeline.
// ===========================================================================
__global__ __launch_bounds__(256) void conv23_gather(
    const float* __restrict__ h, const float* __restrict__ ea,
    const float* __restrict__ We2, const float* __restrict__ be2,
    const float* __restrict__ We3, const float* __restrict__ be3,
    const int* __restrict__ off, const int2* __restrict__ perm2,
    float* __restrict__ aggr2, float* __restrict__ aggr3)
{
    // row k of sW holds [ W2 row k : 32 float2 | W3 row k : 32 float2 ]
    __shared__ float2 sW[16 * 64];
    __shared__ float2 sb[64];
    int t = threadIdx.x;
    for (int i = t; i < 512; i += 256) {
        int k = i >> 5, c = i & 31;
        sW[(k << 6) + c]      = ((const float2*)We2)[i];
        sW[(k << 6) + 32 + c] = ((const float2*)We3)[i];
    }
    if (t < 32) { sb[t] = ((const float2*)be2)[t]; sb[32 + t] = ((const float2*)be3)[t]; }
    __syncthreads();

    int lane = t & 63;
    int half = lane >> 5;            // 0 = mu tree, 1 = logstd tree
    int c2 = (lane & 31) << 1;       // channel pair within the tree
    int n = blockIdx.x * 4 + (t >> 6);
    if (n >= NN) return;
    int j0 = off[n], j1 = off[n + 1];
    float2 bias = sb[lane];
    float2 acc = make_float2(0.f, 0.f);

    int2 es1 = make_int2(0, 0);
    float4 c0, c1, c2v, c3; float2 ch;
    c0 = c1 = c2v = c3 = make_float4(0.f, 0.f, 0.f, 0.f);
    ch = make_float2(0.f, 0.f);
    if (j0 < j1) {
        int2 es0 = perm2[j0];
        int e = __builtin_amdgcn_readfirstlane(es0.x);
        int s = __builtin_amdgcn_readfirstlane(es0.y);
        const float4* ap = (const float4*)(ea + (size_t)e * 16);
        c0 = ap[0]; c1 = ap[1]; c2v = ap[2]; c3 = ap[3];
        ch = *(const float2*)(h + (size_t)s * 64 + c2);
        if (j0 + 1 < j1) es1 = perm2[j0 + 1];
    }
    for (int j = j0; j < j1; j++) {
        float4 p0, p1, p2, p3; float2 ph; int2 es2 = es1;
        p0 = c0; p1 = c1; p2 = c2v; p3 = c3; ph = ch;
        if (j + 1 < j1) {
            int e = __builtin_amdgcn_readfirstlane(es1.x);
            int s = __builtin_amdgcn_readfirstlane(es1.y);
            const float4* ap = (const float4*)(ea + (size_t)e * 16);
            p0 = ap[0]; p1 = ap[1]; p2 = ap[2]; p3 = ap[3];
            ph = *(const float2*)(h + (size_t)s * 64 + c2);
            if (j + 2 < j1) es2 = perm2[j + 2];
        }
        float av[16] = {c0.x,c0.y,c0.z,c0.w, c1.x,c1.y,c1.z,c1.w,
                        c2v.x,c2v.y,c2v.z,c2v.w, c3.x,c3.y,c3.z,c3.w};
        float2 m = bias;
        #pragma unroll
        for (int k = 0; k < 16; k++) {
            float2 w = sW[(k << 6) + lane];
            m.x = fmaf(av[k], w.x, m.x);
            m.y = fmaf(av[k], w.y, m.y);
        }
        acc.x += fmaxf(ch.x + m.x, 0.0f);
        acc.y += fmaxf(ch.y + m.y, 0.0f);
        c0 = p0; c1 = p1; c2v = p2; c3 = p3; ch = ph;
        es1 = es2;
    }
    float* dstp = (half ? aggr3 : aggr2) + (size_t)n * 64 + c2;
    *(float2*)dstp = acc;
}

// ===========================================================================
// Node MLP: out = epilogue( relu((xin+aggr) @ Wa + ba) @ Wb + bb )
// KIN -> 64 -> 64. 64 nodes per block, 256 threads, 4x4 register tiles.
// mode: 0 = none, 1 = relu, 2 = clip(-10, 10)
// ===========================================================================
template <int KIN>
__global__ __launch_bounds__(256) void node_mlp(
    const float* __restrict__ xin, const float* __restrict__ aggr,
    const float* __restrict__ Wa, const float* __restrict__ ba,
    const float* __restrict__ Wb, const float* __restrict__ bb,
    float* __restrict__ out, int mode)
{
    constexpr int S0 = KIN + 4;
    constexpr int K4 = KIN / 4;
    __shared__ float sWa[KIN * 64];
    __shared__ float sWb[64 * 64];
    __shared__ float sh[64 * S0];
    __shared__ float sba[64], sbb[64];
    int t = threadIdx.x;
    for (int i = t; i < KIN * 16; i += 256) ((float4*)sWa)[i] = ((const float4*)Wa)[i];
    for (int i = t; i < 1024; i += 256)     ((float4*)sWb)[i] = ((const float4*)Wb)[i];
    if (t < 64) { sba[t] = ba[t]; sbb[t] = bb[t]; }

    int nb = blockIdx.x << 6;
    for (int i = t; i < 64 * K4; i += 256) {
        int n = i / K4, k4 = i % K4;
        int node = nb + n;
        float4 v = make_float4(0.f, 0.f, 0.f, 0.f);
        if (node < NN) {
            float4 a = ((const float4*)(xin  + (size_t)node * KIN))[k4];
            float4 b = ((const float4*)(aggr + (size_t)node * KIN))[k4];
            v = make_float4(a.x + b.x, a.y + b.y, a.z + b.z, a.w + b.w);
        }
        *(float4*)&sh[n * S0 + (k4 << 2)] = v;
    }
    __syncthreads();

    int tx = t & 15, ty = t >> 4;
    int c0 = tx << 2, n0 = ty << 2;

    float4 b1 = *(const float4*)&sba[c0];
    float acc[4][4];
    #pragma unroll
    for (int i = 0; i < 4; i++) { acc[i][0] = b1.x; acc[i][1] = b1.y; acc[i][2] = b1.z; acc[i][3] = b1.w; }
    for (int k4 = 0; k4 < K4; k4++) {
        int k = k4 << 2;
        float4 w0 = *(const float4*)&sWa[((k + 0) << 6) + c0];
        float4 w1 = *(const float4*)&sWa[((k + 1) << 6) + c0];
        float4 w2 = *(const float4*)&sWa[((k + 2) << 6) + c0];
        float4 w3 = *(const float4*)&sWa[((k + 3) << 6) + c0];
        #pragma unroll
        for (int i = 0; i < 4; i++) {
            float4 hv = *(const float4*)&sh[(n0 + i) * S0 + k];
            acc[i][0] = fmaf(hv.x, w0.x, acc[i][0]); acc[i][1] = fmaf(hv.x, w0.y, acc[i][1]);
            acc[i][2] = fmaf(hv.x, w0.z, acc[i][2]); acc[i][3] = fmaf(hv.x, w0.w, acc[i][3]);
            acc[i][0] = fmaf(hv.y, w1.x, acc[i][0]); acc[i][1] = fmaf(hv.y, w1.y, acc[i][1]);
            acc[i][2] = fmaf(hv.y, w1.z, acc[i][2]); acc[i][3] = fmaf(hv.y, w1.w, acc[i][3]);
            acc[i][0] = fmaf(hv.z, w2.x, acc[i][0]); acc[i][1] = fmaf(hv.z, w2.y, acc[i][1]);
            acc[i][2] = fmaf(hv.z, w2.z, acc[i][2]); acc[i][3] = fmaf(hv.z, w2.w, acc[i][3]);
            acc[i][0] = fmaf(hv.w, w3.x, acc[i][0]); acc[i][1] = fmaf(hv.w, w3.y, acc[i][1]);
            acc[i][2] = fmaf(hv.w, w3.z, acc[i][2]); acc[i][3] = fmaf(hv.w, w3.w, acc[i][3]);
        }
    }
    __syncthreads();
    #pragma unroll
    for (int i = 0; i < 4; i++) {
        float4 v = make_float4(fmaxf(acc[i][0], 0.f), fmaxf(acc[i][1], 0.f),
                               fmaxf(acc[i][2], 0.f), fmaxf(acc[i][3], 0.f));
        *(float4*)&sh[(n0 + i) * 68 + c0] = v;
    }
    __syncthreads();

    float4 b2 = *(const float4*)&sbb[c0];
    float acc2[4][4];
    #pragma unroll
    for (int i = 0; i < 4; i++) { acc2[i][0] = b2.x; acc2[i][1] = b2.y; acc2[i][2] = b2.z; acc2[i][3] = b2.w; }
    for (int k4 = 0; k4 < 16; k4++) {
        int k = k4 << 2;
        float4 w0 = *(const float4*)&sWb[((k + 0) << 6) + c0];
        float4 w1 = *(const float4*)&sWb[((k + 1) << 6) + c0];
        float4 w2 = *(const float4*)&sWb[((k + 2) << 6) + c0];
        float4 w3 = *(const float4*)&sWb[((k + 3) << 6) + c0];
        #pragma unroll
        for (int i = 0; i < 4; i++) {
            float4 hv = *(const float4*)&sh[(n0 + i) * 68 + k];
            acc2[i][0] = fmaf(hv.x, w0.x, acc2[i][0]); acc2[i][1] = fmaf(hv.x, w0.y, acc2[i][1]);
            acc2[i][2] = fmaf(hv.x, w0.z, acc2[i][2]); acc2[i][3] = fmaf(hv.x, w0.w, acc2[i][3]);
            acc2[i][0] = fmaf(hv.y, w1.x, acc2[i][0]); acc2[i][1] = fmaf(hv.y, w1.y, acc2[i][1]);
            acc2[i][2] = fmaf(hv.y, w1.z, acc2[i][2]); acc2[i][3] = fmaf(hv.y, w1.w, acc2[i][3]);
            acc2[i][0] = fmaf(hv.z, w2.x, acc2[i][0]); acc2[i][1] = fmaf(hv.z, w2.y, acc2[i][1]);
            acc2[i][2] = fmaf(hv.z, w2.z, acc2[i][2]); acc2[i][3] = fmaf(hv.z, w2.w, acc2[i][3]);
            acc2[i][0] = fmaf(hv.w, w3.x, acc2[i][0]); acc2[i][1] = fmaf(hv.w, w3.y, acc2[i][1]);
            acc2[i][2] = fmaf(hv.w, w3.z, acc2[i][2]); acc2[i][3] = fmaf(hv.w, w3.w, acc2[i][3]);
        }
    }

    #pragma unroll
    for (int i = 0; i < 4; i++) {
        int node = nb + n0 + i;
        if (node >= NN) continue;
        float4 v = make_float4(acc2[i][0], acc2[i][1], acc2[i][2], acc2[i][3]);
        if (mode == 1) {
            v = make_float4(fmaxf(v.x, 0.f), fmaxf(v.y, 0.f), fmaxf(v.z, 0.f), fmaxf(v.w, 0.f));
        } else if (mode == 2) {
            v = make_float4(fminf(fmaxf(v.x, -10.f), 10.f), fminf(fmaxf(v.y, -10.f), 10.f),
                            fminf(fmaxf(v.z, -10.f), 10.f), fminf(fmaxf(v.w, -10.f), 10.f));
        }
        *(float4*)(out + (size_t)node * 64 + c0) = v;
    }
}

extern "C" void kernel_launch(void* const* d_in, const int* in_sizes, int n_in,
                              void* d_out, int out_size, void* d_ws, size_t ws_size,
                              hipStream_t stream)
{
    const float* x   = (const float*)d_in[0];
    const int*   ei  = (const int*)  d_in[1];
    const float* ea  = (const float*)d_in[2];
    const float* We1 = (const float*)d_in[3];
    const float* be1 = (const float*)d_in[4];
    const float* W1a = (const float*)d_in[5];
    const float* b1a = (const float*)d_in[6];
    const float* W1b = (const float*)d_in[7];
    const float* b1b = (const float*)d_in[8];
    const float* We2 = (const float*)d_in[9];
    const float* be2 = (const float*)d_in[10];
    const float* W2a = (const float*)d_in[11];
    const float* b2a = (const float*)d_in[12];
    const float* W2b = (const float*)d_in[13];
    const float* b2b = (const float*)d_in[14];
    const float* We3 = (const float*)d_in[15];
    const float* be3 = (const float*)d_in[16];
    const float* W3a = (const float*)d_in[17];
    const float* b3a = (const float*)d_in[18];
    const float* W3b = (const float*)d_in[19];
    const float* b3b = (const float*)d_in[20];

    float* out = (float*)d_out;
    float* ws = (float*)d_ws;
    // float scratch: aggr1 [12.8M] (later aliased by aggr2/aggr3), h [6.4M]
    float* aggr1 = ws;
    float* h     = ws + 12800000;
    float* aggr2 = ws;              // aliases aggr1 (dead after node_mlp<128>)
    float* aggr3 = ws + 6400000;
    // int scratch after 19.2M floats: off [NN+1], cur [NN], perm2 [2*NE]
    int* ibase = (int*)(ws + 19200000);
    int* off   = ibase;
    int* cur   = ibase + (NN + 1);
    int2* perm2 = (int2*)(ibase + (2 * NN + 2));

    // ---- CSR build (shared by conv1 and conv23) ----
    hipMemsetAsync(cur, 0, (size_t)NN * sizeof(int), stream);
    hist_dst<<<2048, 256, 0, stream>>>(ei, cur);
    scan_deg<<<1, 1024, 0, stream>>>(cur, off);   // cur becomes scatter cursor
    scatter_perm<<<2048, 256, 0, stream>>>(ei, cur, perm2);

    // ---- layer 1 ----
    conv1_gather<<<(NN + 3) / 4, 256, 0, stream>>>(x, ea, We1, be1, off, perm2, aggr1);
    node_mlp<128><<<(NN + 63) / 64, 256, 0, stream>>>(x, aggr1, W1a, b1a, W1b, b1b, h, 1);

    // ---- layers 2+3 (fused edge pass) ----
    conv23_gather<<<(NN + 3) / 4, 256, 0, stream>>>(h, ea, We2, be2, We3, be3,
                                                    off, perm2, aggr2, aggr3);
    node_mlp<64><<<(NN + 63) / 64, 256, 0, stream>>>(h, aggr2, W2a, b2a, W2b, b2b, out, 0);
    node_mlp<64><<<(NN + 63) / 64, 256, 0, stream>>>(h, aggr3, W3a, b3a, W3b, b3b,
                                                     out + (size_t)NN * 64, 2);
}